// Round 8
// baseline (1967.224 us; speedup 1.0000x reference)
//
#include <hip/hip_runtime.h>

#define SEQ 512
#define BATCH 64
#define NN 1024
#define SS 64
#define NGRP 16   // groups of 64 neurons; one single-wave block per group per batch

// ---- transpose W1 (1024x1024 f32) into workspace: W1T[i*N+j] = W1[j*N+i] ----
__global__ void transpose1(const float* __restrict__ A, float* __restrict__ At) {
    __shared__ float tile[32][33];
    int bx = blockIdx.x * 32, by = blockIdx.y * 32;
    int tx = threadIdx.x, ty = threadIdx.y;   // block 32x8
#pragma unroll
    for (int r = 0; r < 32; r += 8)
        tile[ty + r][tx] = A[(by + ty + r) * NN + (bx + tx)];
    __syncthreads();
#pragma unroll
    for (int r = 0; r < 32; r += 8)
        At[(bx + ty + r) * NN + (by + tx)] = tile[tx][ty + r];
}

// 16-lane inclusive prefix scan via DPP row_shr (pure VALU).
__device__ __forceinline__ int dpp_scan16(int x) {
    x += __builtin_amdgcn_update_dpp(0, x, 0x111, 0xF, 0xF, false); // row_shr:1
    x += __builtin_amdgcn_update_dpp(0, x, 0x112, 0xF, 0xF, false); // row_shr:2
    x += __builtin_amdgcn_update_dpp(0, x, 0x114, 0xF, 0xF, false); // row_shr:4
    x += __builtin_amdgcn_update_dpp(0, x, 0x118, 0xF, 0xF, false); // row_shr:8
    return x;
}

#define ALOAD(p)    __hip_atomic_load((p), __ATOMIC_RELAXED, __HIP_MEMORY_SCOPE_AGENT)
#define ASTORE(p,v) __hip_atomic_store((p), (v), __ATOMIC_RELAXED, __HIP_MEMORY_SCOPE_AGENT)

// ---- main LIF kernel: grid = NGRP*BATCH single-wave blocks.
// bid = g*64 + b  =>  all 16 partner blocks of a batch share bid%8 (XCD locality
// heuristic only; correctness uses agent-scope atomics throughout).
// No LDS, no barriers: cross-block prefix via tagged atomic count exchange.
__global__ __launch_bounds__(64, 1) void lif_kernel(
    const float* __restrict__ W1T, const float* __restrict__ W2,
    const float* __restrict__ decay1, const float* __restrict__ decay2,
    const float* __restrict__ th1, const float* __restrict__ th2,
    const float* __restrict__ init1, const float* __restrict__ init2,
    const int* __restrict__ inp_ids, const int* __restrict__ inp_num,
    unsigned* __restrict__ c1g, unsigned* __restrict__ c2g,
    unsigned* __restrict__ c1bg, int* __restrict__ spkg,
    float* __restrict__ out)
{
    const int bid  = blockIdx.x;
    const int g    = bid >> 6;          // neuron group 0..15
    const int b    = bid & 63;          // batch element
    const int lane = threadIdx.x;       // 0..63
    const int n    = (g << 6) + lane;   // my neuron

    unsigned* c1  = c1g  + b * 32;      // 16 u32 used, 128B stride per batch
    unsigned* c2  = c2g  + b * 32;
    unsigned* c1b = c1bg + b * 32;
    int*      spk = spkg + b * NN;

    float v1 = init1[b * NN + n];
    float v2 = init2[b * NN + n];
    const float d1 = decay1[n], d2 = decay2[n];
    const float t1 = th1[n],    t2 = th2[n];
    const float t1b = __fmul_rn(0.9f, t1);
    const float t2b = __fmul_rn(0.9f, t2);
    const float omd1 = __fadd_rn(1.0f, -d1);
    const float omd2 = __fadd_rn(1.0f, -d2);

    // output layout (floats): ids1 | ids2 | cnt1 | cnt2 | st1 | st2
    float* out_ids1 = out;
    float* out_ids2 = out + (size_t)SEQ * BATCH * SS;
    float* out_cnt1 = out + (size_t)2 * SEQ * BATCH * SS;
    float* out_cnt2 = out_cnt1 + (size_t)SEQ * BATCH * 2;
    float* out_st1  = out_cnt2 + (size_t)SEQ * BATCH * 2;
    float* out_st2  = out_st1  + (size_t)SEQ * BATCH * NN;

    const unsigned long long lmask_lt = (1ull << lane) - 1ull;

    // ---- prologue: num/ids pipelines + gather(0) ----
    int num_cur = inp_num[b];
    int num_nx  = inp_num[BATCH + b];
    int idv_a   = inp_ids[((size_t)BATCH + b) * SS + lane];   // ids(1)[lane]
    float a[64];
    {
        const int* ids0 = inp_ids + (size_t)b * SS;           // uniform -> s_load
        const int nch = (num_cur + 15) >> 4;
#pragma unroll
        for (int c = 0; c < 4; ++c)
            if (c < nch)
#pragma unroll
                for (int j = 0; j < 16; ++j)
                    a[c * 16 + j] = W1T[((size_t)ids0[c * 16 + j] << 10) + n];
    }

    for (int t = 0; t < SEQ; ++t) {
        const int tn2 = (t + 2 < SEQ) ? t + 2 : 0;            // wrap: harmless loads
        const int idv_b  = inp_ids[((size_t)tn2 * BATCH + b) * SS + lane]; // ids(t+2)
        const int num_n2 = inp_num[tn2 * BATCH + b];                       // num(t+2)
        const int nch_nx = (num_nx + 15) >> 4;

        // ---- accumulate gather(t) chunk c, then issue chunk c of gather(t+1) ----
        float I1;
        {
            float s0 = 0.0f, s1 = 0.0f, s2 = 0.0f, s3 = 0.0f;
#pragma unroll
            for (int c = 0; c < 4; ++c) {
                const int lim = num_cur - (c << 4);
                if (lim >= 16) {
#pragma unroll
                    for (int j = 0; j < 16; j += 4) {
                        s0 = __fadd_rn(s0, a[c * 16 + j + 0]);
                        s1 = __fadd_rn(s1, a[c * 16 + j + 1]);
                        s2 = __fadd_rn(s2, a[c * 16 + j + 2]);
                        s3 = __fadd_rn(s3, a[c * 16 + j + 3]);
                    }
                } else if (lim > 0) {
#pragma unroll
                    for (int j = 0; j < 16; j += 4) {
                        s0 = __fadd_rn(s0, (j + 0 < lim) ? a[c * 16 + j + 0] : 0.0f);
                        s1 = __fadd_rn(s1, (j + 1 < lim) ? a[c * 16 + j + 1] : 0.0f);
                        s2 = __fadd_rn(s2, (j + 2 < lim) ? a[c * 16 + j + 2] : 0.0f);
                        s3 = __fadd_rn(s3, (j + 3 < lim) ? a[c * 16 + j + 3] : 0.0f);
                    }
                }
                if (c < nch_nx) {
#pragma unroll
                    for (int j = 0; j < 16; ++j) {
                        const int sid = __builtin_amdgcn_readlane(idv_a, c * 16 + j);
                        a[c * 16 + j] = W1T[((size_t)sid << 10) + n];
                    }
                }
            }
            I1 = __fadd_rn(__fadd_rn(s0, s1), __fadd_rn(s2, s3));
        }

        // ---- layer 1 update + publish group count ----
        v1 = __fadd_rn(__fmul_rn(d1, v1), __fmul_rn(omd1, I1));
        const bool spk1 = v1 > t1;
        const unsigned long long bal1 = __ballot(spk1);
        const unsigned long long bal2 = __ballot(v1 > t1b);
        const unsigned exp1  = (unsigned)((t + 1) & 0xFF);
        const unsigned exp2p = (unsigned)((t + 1) & 0x7F);
        if (lane == 0)
            ASTORE(&c1[g], (exp1 << 24) | ((unsigned)__popcll(bal2) << 12)
                                        | (unsigned)__popcll(bal1));

        // ---- speculative layer 2 (I2 = 0; exact when no layer-1 spikes) ----
        const float v2s = __fmul_rn(d2, v2);
        {
            const unsigned long long c3 = __ballot(v2s > t2);
            const unsigned long long c4 = __ballot(v2s > t2b);
            if (lane == 0)
                ASTORE(&c2[g], (exp2p << 24) | ((unsigned)__popcll(c4) << 12)
                                             | (unsigned)__popcll(c3));
        }

        // ---- phase-1 exchange: spin on all 16 group slots, then DPP scan ----
        unsigned w1v;
        for (;;) {
            w1v = ALOAD(&c1[lane & 15]);
            if (__all((int)(w1v >> 24) == (int)exp1)) break;
            __builtin_amdgcn_s_sleep(1);
        }
        int xA = dpp_scan16((int)(w1v & 0xFFFFFF));
        const int totPackA = __builtin_amdgcn_readlane(xA, 15);
        const int offPackA = g ? __builtin_amdgcn_readlane(xA, g - 1) : 0;
        const int totalA  = totPackA & 0xFFF;
        const int total2A = (totPackA >> 12) & 0xFFF;
        const int spk_lt1 = (offPackA & 0xFFF) + (int)__popcll(bal1 & lmask_lt);
        const int slot1   = spk1 ? spk_lt1 : (totalA + n - spk_lt1);
        if (spk1) v1 = 0.0f;

        // ---- layer 2 resolve: accept speculation, or rare corrective path ----
        bool spk2;
        if (totalA > 0) {
            if (spk1) ASTORE((unsigned*)&spk[spk_lt1], (unsigned)n);
            __threadfence();
            if (lane == 0)
                __hip_atomic_store(&c1b[g], (unsigned)(t + 1),
                                   __ATOMIC_RELEASE, __HIP_MEMORY_SCOPE_AGENT);
            for (;;) {
                unsigned dv = __hip_atomic_load(&c1b[lane & 15],
                                   __ATOMIC_ACQUIRE, __HIP_MEMORY_SCOPE_AGENT);
                if (__all(dv == (unsigned)(t + 1))) break;
                __builtin_amdgcn_s_sleep(1);
            }
            float I2 = 0.0f;
            for (int kb = 0; kb < totalA; kb += 64) {
                int idw = 0;
                if (kb + lane < totalA)
                    idw = (int)ALOAD((unsigned*)&spk[kb + lane]);
                const int kmax = (totalA - kb) < 64 ? (totalA - kb) : 64;
                for (int j = 0; j < kmax; ++j) {
                    const int sid = __builtin_amdgcn_readlane(idw, j);
                    I2 = __fadd_rn(I2, W2[(size_t)n * NN + sid]); // W2T[sid][n]
                }
            }
            const float v2r = __fadd_rn(__fmul_rn(d2, v2), __fmul_rn(omd2, I2));
            spk2 = v2r > t2;
            const unsigned long long c3 = __ballot(spk2);
            const unsigned long long c4 = __ballot(v2r > t2b);
            if (lane == 0)
                ASTORE(&c2[g], ((0x80u | exp2p) << 24)
                               | ((unsigned)__popcll(c4) << 12)
                               | (unsigned)__popcll(c3));
            v2 = v2r;
        } else {
            v2 = v2s;
            spk2 = v2 > t2;
        }
        const unsigned long long bal3 = __ballot(spk2);

        // ---- phase-2 exchange (expected tag encodes spec vs corrected) ----
        const unsigned exp2 = (totalA > 0) ? (0x80u | exp2p) : exp2p;
        unsigned w2v;
        for (;;) {
            w2v = ALOAD(&c2[lane & 15]);
            if (__all((int)(w2v >> 24) == (int)exp2)) break;
            __builtin_amdgcn_s_sleep(1);
        }
        int xB = dpp_scan16((int)(w2v & 0xFFFFFF));
        const int totPackB = __builtin_amdgcn_readlane(xB, 15);
        const int offPackB = g ? __builtin_amdgcn_readlane(xB, g - 1) : 0;
        const int totalB   = totPackB & 0xFFF;
        const int total2B  = (totPackB >> 12) & 0xFFF;
        const int spk_lt2  = (offPackB & 0xFFF) + (int)__popcll(bal3 & lmask_lt);
        const int slot2    = spk2 ? spk_lt2 : (totalB + n - spk_lt2);
        if (spk2) v2 = 0.0f;

        // ---- stores for step t (NT, fire-and-forget) ----
        const size_t row = (size_t)t * BATCH + b;
        if (slot1 < SS)
            __builtin_nontemporal_store((float)n, &out_ids1[row * SS + slot1]);
        if (slot2 < SS)
            __builtin_nontemporal_store((float)n, &out_ids2[row * SS + slot2]);
        if (g == 0 && lane == 0) {
            __builtin_nontemporal_store((float)totalA,  &out_cnt1[row * 2 + 0]);
            __builtin_nontemporal_store((float)total2A, &out_cnt1[row * 2 + 1]);
            __builtin_nontemporal_store((float)totalB,  &out_cnt2[row * 2 + 0]);
            __builtin_nontemporal_store((float)total2B, &out_cnt2[row * 2 + 1]);
        }
        __builtin_nontemporal_store(v1, &out_st1[row * NN + n]);
        __builtin_nontemporal_store(v2, &out_st2[row * NN + n]);

        // ---- rotate pipelines ----
        num_cur = num_nx;
        num_nx  = num_n2;
        idv_a   = idv_b;
    }
}

extern "C" void kernel_launch(void* const* d_in, const int* in_sizes, int n_in,
                              void* d_out, int out_size, void* d_ws, size_t ws_size,
                              hipStream_t stream) {
    const float* W1     = (const float*)d_in[0];
    const float* W2     = (const float*)d_in[1];
    const float* decay1 = (const float*)d_in[2];
    const float* decay2 = (const float*)d_in[3];
    const float* th1    = (const float*)d_in[4];
    const float* th2    = (const float*)d_in[5];
    const float* init1  = (const float*)d_in[6];
    const float* init2  = (const float*)d_in[7];
    const int* inp_ids  = (const int*)d_in[8];
    const int* inp_num  = (const int*)d_in[9];
    float* out = (float*)d_out;

    float* W1T = (float*)d_ws;                       // 4 MB
    char*  comm = (char*)d_ws + (size_t)NN * NN * 4; // comm region after W1T
    unsigned* c1g  = (unsigned*)(comm);              // 64 batches * 128B
    unsigned* c2g  = (unsigned*)(comm + 8192);
    unsigned* c1bg = (unsigned*)(comm + 16384);
    int*      spkg = (int*)(comm + 32768);           // 64 * 1024 * 4 = 256KB
    // zero tags/flags each launch (previous dispatch left stale generations)
    hipMemsetAsync(comm, 0, 32768 + (size_t)BATCH * NN * 4, stream);

    dim3 tb(32, 8, 1), tg(NN / 32, NN / 32, 1);
    transpose1<<<tg, tb, 0, stream>>>(W1, W1T);
    lif_kernel<<<NGRP * BATCH, 64, 0, stream>>>(W1T, W2, decay1, decay2, th1, th2,
                                                init1, init2, inp_ids, inp_num,
                                                c1g, c2g, c1bg, spkg, out);
}

// Round 9
// 1491.223 us; speedup vs baseline: 1.3192x; 1.3192x over previous
//
#include <hip/hip_runtime.h>

#define SEQ 512
#define BATCH 64
#define NN 1024
#define SS 64
#define NT 512            // threads per block; block h covers neurons h*512..h*512+511

typedef unsigned long long u64;

// lgkm-only barrier (no vmcnt drain) — rare path only
#define RAW_BARRIER() asm volatile("s_waitcnt lgkmcnt(0)\n\ts_barrier" ::: "memory")

#define ALOAD64(p)    __hip_atomic_load((p), __ATOMIC_RELAXED, __HIP_MEMORY_SCOPE_AGENT)
#define ASTORE64(p,v) __hip_atomic_store((p), (v), __ATOMIC_RELAXED, __HIP_MEMORY_SCOPE_AGENT)
#define ALOAD32(p)    __hip_atomic_load((p), __ATOMIC_RELAXED, __HIP_MEMORY_SCOPE_AGENT)
#define ASTORE32(p,v) __hip_atomic_store((p), (v), __ATOMIC_RELAXED, __HIP_MEMORY_SCOPE_AGENT)

// ---- transpose W1 (1024x1024 f32): W1T[i*N+j] = W1[j*N+i] ----
__global__ void transpose1(const float* __restrict__ A, float* __restrict__ At) {
    __shared__ float tile[32][33];
    int bx = blockIdx.x * 32, by = blockIdx.y * 32;
    int tx = threadIdx.x, ty = threadIdx.y;   // block 32x8
#pragma unroll
    for (int r = 0; r < 32; r += 8)
        tile[ty + r][tx] = A[(by + ty + r) * NN + (bx + tx)];
    __syncthreads();
#pragma unroll
    for (int r = 0; r < 32; r += 8)
        At[(bx + ty + r) * NN + (by + tx)] = tile[tx][ty + r];
}

// 16-lane inclusive prefix scan via DPP row_shr (pure VALU).
__device__ __forceinline__ int dpp_scan16(int x) {
    x += __builtin_amdgcn_update_dpp(0, x, 0x111, 0xF, 0xF, false); // row_shr:1
    x += __builtin_amdgcn_update_dpp(0, x, 0x112, 0xF, 0xF, false); // row_shr:2
    x += __builtin_amdgcn_update_dpp(0, x, 0x114, 0xF, 0xF, false); // row_shr:4
    x += __builtin_amdgcn_update_dpp(0, x, 0x118, 0xF, 0xF, false); // row_shr:8
    return x;
}

// ---- main LIF kernel: 2 blocks per batch (halves of the neuron dim).
// bid = h*64 + b  => partners share bid%8 (XCD-locality heuristic only; all
// cross-block traffic uses agent-scope atomics, so correctness is placement-free).
// Common path: NO barrier, NO LDS — per-wave tagged 64-bit word exchange.
// Word: [t+1:16][pB:24][pA:24]; p = cnt | cnt2<<12. Parity slots ([t&1]) +
// launch-unique tags make the exchange overwrite- and deadlock-free.
__global__ __launch_bounds__(NT, 2) void lif_kernel(
    const float* __restrict__ W1T, const float* __restrict__ W2,
    const float* __restrict__ decay1, const float* __restrict__ decay2,
    const float* __restrict__ th1, const float* __restrict__ th2,
    const float* __restrict__ init1, const float* __restrict__ init2,
    const int* __restrict__ inp_ids, const int* __restrict__ inp_num,
    u64* __restrict__ cwt, u64* __restrict__ ccorr, u64* __restrict__ cwt2,
    int* __restrict__ spkg, float* __restrict__ out)
{
    const int bid  = blockIdx.x;
    const int h    = bid >> 6;            // half: 0 or 1
    const int b    = bid & 63;            // batch element
    const int i    = threadIdx.x;         // 0..511
    const int lane = i & 63;
    const int wid  = i >> 6;              // 0..7
    const int n    = (h << 9) + i;        // my neuron
    const int G    = (h << 3) + wid;      // global group 0..15

    u64* wtb  = cwt  + (size_t)b * 32;    // [parity][16]
    u64* wtb2 = cwt2 + (size_t)b * 32;    // [parity][16] (rare corrected-B)
    u64* corr = ccorr + (size_t)b * 4;    // [parity][2]  (rare list-ready)
    int* spk  = spkg + b * NN;

    float v1 = init1[b * NN + n];
    float v2 = init2[b * NN + n];
    const float d1 = decay1[n], d2 = decay2[n];
    const float t1 = th1[n],    t2 = th2[n];
    const float t1b = __fmul_rn(0.9f, t1);
    const float t2b = __fmul_rn(0.9f, t2);
    const float omd1 = __fadd_rn(1.0f, -d1);
    const float omd2 = __fadd_rn(1.0f, -d2);

    // output layout (floats): ids1 | ids2 | cnt1 | cnt2 | st1 | st2
    float* out_ids1 = out;
    float* out_ids2 = out + (size_t)SEQ * BATCH * SS;
    float* out_cnt1 = out + (size_t)2 * SEQ * BATCH * SS;
    float* out_cnt2 = out_cnt1 + (size_t)SEQ * BATCH * 2;
    float* out_st1  = out_cnt2 + (size_t)SEQ * BATCH * 2;
    float* out_st2  = out_st1  + (size_t)SEQ * BATCH * NN;

    const unsigned long long lmask_lt = (1ull << lane) - 1ull;

    // ---- prologue: gather(0) via scalar ids, 8-granular ----
    int num_cur = inp_num[b];
    float a[64];
    {
        const int* ids0 = inp_ids + (size_t)b * SS;      // uniform -> s_load path
        const int nch = (num_cur + 7) >> 3;
#pragma unroll
        for (int c = 0; c < 8; ++c)
            if (c < nch)
#pragma unroll
                for (int j = 0; j < 8; ++j)
                    a[c * 8 + j] = W1T[((size_t)ids0[c * 8 + j] << 10) + n];
    }

    for (int t = 0; t < SEQ; ++t) {
        const int par = t & 1;
        const u64 tag = (u64)(t + 1);                    // launch-unique (memset 0)
        const int tn  = (t + 1 < SEQ) ? t + 1 : 0;       // wrap: tail loads harmless
        const int num_next = inp_num[tn * BATCH + b];
        const int* idsn = inp_ids + ((size_t)tn * BATCH + b) * SS;

        // ---- layer 1 accumulate from resident a[] (8-granular masking) ----
        float I1;
        {
            float s0 = 0.0f, s1 = 0.0f, s2 = 0.0f, s3 = 0.0f;
#pragma unroll
            for (int c = 0; c < 8; ++c) {
                const int lim = num_cur - (c << 3);
                if (lim >= 8) {
#pragma unroll
                    for (int j = 0; j < 8; j += 4) {
                        s0 = __fadd_rn(s0, a[c * 8 + j + 0]);
                        s1 = __fadd_rn(s1, a[c * 8 + j + 1]);
                        s2 = __fadd_rn(s2, a[c * 8 + j + 2]);
                        s3 = __fadd_rn(s3, a[c * 8 + j + 3]);
                    }
                } else if (lim > 0) {
#pragma unroll
                    for (int j = 0; j < 8; j += 4) {
                        s0 = __fadd_rn(s0, (j + 0 < lim) ? a[c * 8 + j + 0] : 0.0f);
                        s1 = __fadd_rn(s1, (j + 1 < lim) ? a[c * 8 + j + 1] : 0.0f);
                        s2 = __fadd_rn(s2, (j + 2 < lim) ? a[c * 8 + j + 2] : 0.0f);
                        s3 = __fadd_rn(s3, (j + 3 < lim) ? a[c * 8 + j + 3] : 0.0f);
                    }
                }
            }
            I1 = __fadd_rn(__fadd_rn(s0, s1), __fadd_rn(s2, s3));
        }

        // ---- layer 1 update + spec layer 2, then ONE per-wave publish ----
        v1 = __fadd_rn(__fmul_rn(d1, v1), __fmul_rn(omd1, I1));
        const bool spk1 = v1 > t1;
        const unsigned long long bal1 = __ballot(spk1);
        const unsigned long long bal2 = __ballot(v1 > t1b);

        const float v2s = __fmul_rn(d2, v2);             // exact when no L1 spikes
        const unsigned long long sb1 = __ballot(v2s > t2);
        const unsigned long long sb2 = __ballot(v2s > t2b);

        if (lane == 0) {
            const u64 pA = (u64)((unsigned)__popcll(bal1) | ((unsigned)__popcll(bal2) << 12));
            const u64 pB = (u64)((unsigned)__popcll(sb1)  | ((unsigned)__popcll(sb2)  << 12));
            ASTORE64(&wtb[par * 16 + G], (tag << 48) | (pB << 24) | pA);
        }

        // ---- issue gather(t+1): scalar ids path, 8-granular; latency covered
        // by spin + scans + stores + next accumulate lead-in ----
        {
            const int nch = (num_next + 7) >> 3;
#pragma unroll
            for (int c = 0; c < 8; ++c)
                if (c < nch)
#pragma unroll
                    for (int j = 0; j < 8; ++j)
                        a[c * 8 + j] = W1T[((size_t)idsn[c * 8 + j] << 10) + n];
        }

        // ---- single exchange: spin all 16 group words (2 cache lines) ----
        u64 w;
        for (;;) {
            w = ALOAD64(&wtb[par * 16 + (lane & 15)]);
            if (__all((int)(unsigned)(w >> 48) == (t + 1))) break;
            __builtin_amdgcn_s_sleep(1);
        }
        const int pA = (int)(w & 0xFFFFFF);
        const int pB = (int)((w >> 24) & 0xFFFFFF);

        // ---- global scan layer 1 (groups 0..15 in neuron order) ----
        const int xA = dpp_scan16(pA);
        const int totA_pack = __builtin_amdgcn_readlane(xA, 15);
        const int offA = G ? __builtin_amdgcn_readlane(xA, G - 1) : 0;
        const int totalA  = totA_pack & 0xFFF;
        const int total2A = (totA_pack >> 12) & 0xFFF;
        const int spk_lt1 = (offA & 0xFFF) + (int)__popcll(bal1 & lmask_lt);
        const int slot1   = spk1 ? spk_lt1 : (totalA + n - spk_lt1);
        if (spk1) v1 = 0.0f;

        // ---- layer 2 resolve ----
        bool spk2;
        int totalB, total2B, spk_lt2;
        unsigned long long bal3;
        if (totalA > 0) {
            // RARE corrective path (block-uniform branch; barrier is legal)
            if (spk1) ASTORE32(&spk[spk_lt1], n);        // global spike list
            asm volatile("s_waitcnt vmcnt(0)" ::: "memory"); // my stores acked
            RAW_BARRIER();                                // whole block done
            if (i == 0)
                __hip_atomic_store(&corr[par * 2 + h], tag,
                                   __ATOMIC_RELEASE, __HIP_MEMORY_SCOPE_AGENT);
            for (;;) {                                    // partner's list ready?
                u64 cw = __hip_atomic_load(&corr[par * 2 + (1 - h)],
                                           __ATOMIC_ACQUIRE, __HIP_MEMORY_SCOPE_AGENT);
                if (__all((int)(unsigned)cw == (t + 1))) break;
                __builtin_amdgcn_s_sleep(1);
            }
            float I2 = 0.0f;                              // ascending global order
            for (int kb = 0; kb < totalA; kb += 64) {
                int idw = 0;
                if (kb + lane < totalA) idw = ALOAD32(&spk[kb + lane]);
                const int kmax = (totalA - kb) < 64 ? (totalA - kb) : 64;
                for (int j = 0; j < kmax; ++j) {
                    const int sid = __builtin_amdgcn_readlane(idw, j);
                    I2 = __fadd_rn(I2, W2[(size_t)n * NN + sid]);  // W2T[sid][n]
                }
            }
            const float v2r = __fadd_rn(__fmul_rn(d2, v2), __fmul_rn(omd2, I2));
            spk2 = v2r > t2;
            const unsigned long long cb1 = __ballot(spk2);
            const unsigned long long cb2 = __ballot(v2r > t2b);
            if (lane == 0) {
                const u64 q = (u64)((unsigned)__popcll(cb1) | ((unsigned)__popcll(cb2) << 12));
                ASTORE64(&wtb2[par * 16 + G], (tag << 48) | q);
            }
            u64 w2;
            for (;;) {
                w2 = ALOAD64(&wtb2[par * 16 + (lane & 15)]);
                if (__all((int)(unsigned)(w2 >> 48) == (t + 1))) break;
                __builtin_amdgcn_s_sleep(1);
            }
            const int xB = dpp_scan16((int)(w2 & 0xFFFFFF));
            const int totB_pack = __builtin_amdgcn_readlane(xB, 15);
            const int offB = G ? __builtin_amdgcn_readlane(xB, G - 1) : 0;
            totalB  = totB_pack & 0xFFF;
            total2B = (totB_pack >> 12) & 0xFFF;
            bal3 = cb1;
            spk_lt2 = (offB & 0xFFF) + (int)__popcll(bal3 & lmask_lt);
            v2 = v2r;
        } else {
            // common path: accept speculation; scan spec-B counts from same words
            v2 = v2s;
            spk2 = v2 > t2;
            const int xB = dpp_scan16(pB);
            const int totB_pack = __builtin_amdgcn_readlane(xB, 15);
            const int offB = G ? __builtin_amdgcn_readlane(xB, G - 1) : 0;
            totalB  = totB_pack & 0xFFF;
            total2B = (totB_pack >> 12) & 0xFFF;
            bal3 = sb1;
            spk_lt2 = (offB & 0xFFF) + (int)__popcll(bal3 & lmask_lt);
        }
        const int slot2 = spk2 ? spk_lt2 : (totalB + n - spk_lt2);
        if (spk2) v2 = 0.0f;

        // ---- stores for step t (NT, fire-and-forget) ----
        const size_t row = (size_t)t * BATCH + b;
        if (slot1 < SS)
            __builtin_nontemporal_store((float)n, &out_ids1[row * SS + slot1]);
        if (slot2 < SS)
            __builtin_nontemporal_store((float)n, &out_ids2[row * SS + slot2]);
        if (h == 0 && i == 0) {
            __builtin_nontemporal_store((float)totalA,  &out_cnt1[row * 2 + 0]);
            __builtin_nontemporal_store((float)total2A, &out_cnt1[row * 2 + 1]);
            __builtin_nontemporal_store((float)totalB,  &out_cnt2[row * 2 + 0]);
            __builtin_nontemporal_store((float)total2B, &out_cnt2[row * 2 + 1]);
        }
        __builtin_nontemporal_store(v1, &out_st1[row * NN + n]);
        __builtin_nontemporal_store(v2, &out_st2[row * NN + n]);

        num_cur = num_next;
    }
}

extern "C" void kernel_launch(void* const* d_in, const int* in_sizes, int n_in,
                              void* d_out, int out_size, void* d_ws, size_t ws_size,
                              hipStream_t stream) {
    const float* W1     = (const float*)d_in[0];
    const float* W2     = (const float*)d_in[1];
    const float* decay1 = (const float*)d_in[2];
    const float* decay2 = (const float*)d_in[3];
    const float* th1    = (const float*)d_in[4];
    const float* th2    = (const float*)d_in[5];
    const float* init1  = (const float*)d_in[6];
    const float* init2  = (const float*)d_in[7];
    const int* inp_ids  = (const int*)d_in[8];
    const int* inp_num  = (const int*)d_in[9];
    float* out = (float*)d_out;

    float* W1T = (float*)d_ws;                          // 4 MB
    char*  comm = (char*)d_ws + (size_t)NN * NN * 4;
    u64* cwt   = (u64*)(comm);                          // 64 * 2 * 16 * 8 = 16 KB
    u64* cwt2  = (u64*)(comm + 16384);                  // 16 KB
    u64* ccorr = (u64*)(comm + 32768);                  // 64 * 4 * 8 = 2 KB
    int* spkg  = (int*)(comm + 36864);                  // 64 * 1024 * 4 = 256 KB
    // zero tags/flags/list each launch (stale generations from prior dispatch)
    hipMemsetAsync(comm, 0, 36864 + (size_t)BATCH * NN * 4, stream);

    dim3 tb(32, 8, 1), tg(NN / 32, NN / 32, 1);
    transpose1<<<tg, tb, 0, stream>>>(W1, W1T);
    lif_kernel<<<2 * BATCH, NT, 0, stream>>>(W1T, W2, decay1, decay2, th1, th2,
                                             init1, init2, inp_ids, inp_num,
                                             cwt, ccorr, cwt2, spkg, out);
}